// Round 5
// baseline (782.253 us; speedup 1.0000x reference)
//
#include <hip/hip_runtime.h>

// DiffAttnLayer: B=2,N=2048,EMB=1024,H=8,HD=64,FF=4096.
// Inputs fp32 (runtime-detected; bf16 world also supported). Output dtype
// FOLLOWS INPUT dtype (reference is pure jnp: fp32 in -> fp32 out).
// Fast path: MFMA 16x16x32 bf16 GEMMs w/ global_load_lds + XOR swizzle,
// flash differential attention. Workspace: 5 x 8MB slots + scalars @40MB.
//  A: h1 -> ob -> h2        B: q -> g(rows 0..2047)
//  C: k -> x2               D: vT -> W1Th(4MB)+W2Th(4MB)
//  E: WqT|WkT|WvT|WoT -> g(rows 2048..4095)

typedef unsigned short u16;
typedef unsigned int u32;
typedef __attribute__((ext_vector_type(8))) __bf16 bf16x8;
typedef __attribute__((ext_vector_type(4))) float f32x4;
typedef __attribute__((ext_vector_type(4))) u32 u32x4;

#define LOG2E 1.4426950408889634f
#define LAM_INIT 0.355509068f
#define ONE_MINUS_LAM_INIT 0.644490932f

__device__ __forceinline__ float bf2f(u16 x) {
  u32 u = ((u32)x) << 16;
  return __builtin_bit_cast(float, u);
}
__device__ __forceinline__ u16 f2bf(float f) {
  u32 u = __builtin_bit_cast(u32, f);
  u32 r = (u + 0x7FFFu + ((u >> 16) & 1u)) >> 16;
  return (u16)r;
}
__device__ __forceinline__ float ldf(const void* p, size_t i, bool f32) {
  return f32 ? ((const float*)p)[i] : bf2f(((const u16*)p)[i]);
}
// global -> LDS async DMA, 16B/lane; LDS dest = wave-uniform base + lane*16.
__device__ __forceinline__ void async16(const u16* g, u16* l) {
  __builtin_amdgcn_global_load_lds((const __attribute__((address_space(1))) u32*)g,
                                   (__attribute__((address_space(3))) u32*)l, 16, 0, 0);
}
__device__ __forceinline__ bf16x8 ld8(const u16* p) { return *(const bf16x8*)p; }

// ---------------- input-dtype detector (1 = bf16, 0 = fp32) ----------------
__global__ void detect_kernel(const u32* x, int* flag) {
  int e = (x[threadIdx.x] >> 7) & 0xFF;
  unsigned long long m = __ballot(e >= 90 && e <= 150);
  if (threadIdx.x == 0) flag[0] = (__popcll(m) >= 40) ? 1 : 0;
}

// ---------------- lambda ----------------
__global__ void lam_kernel(const void* lq1, const void* lk1, const void* lq2,
                           const void* lk2, const int* flag, float* out) {
  const bool f32 = flag[0] == 0;
  int L = threadIdx.x;
  float a = ldf(lq1, L, f32) * ldf(lk1, L, f32);
  float c = ldf(lq2, L, f32) * ldf(lk2, L, f32);
#pragma unroll
  for (int m = 1; m < 64; m <<= 1) { a += __shfl_xor(a, m); c += __shfl_xor(c, m); }
  if (L == 0) out[0] = __expf(a) - __expf(c) + LAM_INIT;
}

// ---------------- LayerNorm over 1024, one wave per row ----------------
__device__ __forceinline__ void unpack8(u32x4 u, float* f) {
#pragma unroll
  for (int i = 0; i < 4; ++i) {
    f[2 * i] = bf2f((u16)(u[i] & 0xffffu));
    f[2 * i + 1] = bf2f((u16)(u[i] >> 16));
  }
}

template <bool XRAW>
__global__ __launch_bounds__(256) void ln_kernel(const void* __restrict__ x,
                                                 const void* __restrict__ w,
                                                 const void* __restrict__ b,
                                                 const int* __restrict__ flag,
                                                 u16* __restrict__ out) {
  const bool f32 = flag[0] == 0;
  const int row = blockIdx.x * 4 + (threadIdx.x >> 6);
  const int L = threadIdx.x & 63;
  float xv[16];
  if (XRAW && f32) {
    const f32x4* xr = (const f32x4*)((const float*)x + (size_t)row * 1024 + L * 16);
#pragma unroll
    for (int i = 0; i < 4; ++i) {
      f32x4 vv = xr[i];
#pragma unroll
      for (int j = 0; j < 4; ++j) xv[i * 4 + j] = vv[j];
    }
  } else {
    const u16* xr = (const u16*)x + (size_t)row * 1024 + L * 16;
    unpack8(*(const u32x4*)xr, xv);
    unpack8(*(const u32x4*)(xr + 8), xv + 8);
  }
  float s = 0.f, sq = 0.f;
#pragma unroll
  for (int i = 0; i < 16; ++i) { s += xv[i]; sq += xv[i] * xv[i]; }
#pragma unroll
  for (int m = 1; m < 64; m <<= 1) { s += __shfl_xor(s, m); sq += __shfl_xor(sq, m); }
  float mean = s * (1.0f / 1024.0f);
  float var = sq * (1.0f / 1024.0f) - mean * mean;
  float rstd = rsqrtf(var + 1e-5f);
  u32 pk[8];
#pragma unroll
  for (int i = 0; i < 8; ++i) {
    float w0 = ldf(w, L * 16 + 2 * i, f32), w1 = ldf(w, L * 16 + 2 * i + 1, f32);
    float b0 = ldf(b, L * 16 + 2 * i, f32), b1v = ldf(b, L * 16 + 2 * i + 1, f32);
    float v0 = (xv[2 * i] - mean) * rstd * w0 + b0;
    float v1 = (xv[2 * i + 1] - mean) * rstd * w1 + b1v;
    pk[i] = (u32)f2bf(v0) | ((u32)f2bf(v1) << 16);
  }
  u32x4 o0 = {pk[0], pk[1], pk[2], pk[3]};
  u32x4 o1 = {pk[4], pk[5], pk[6], pk[7]};
  *(u32x4*)(out + (size_t)row * 1024 + L * 16) = o0;
  *(u32x4*)(out + (size_t)row * 1024 + L * 16 + 8) = o1;
}

// ---------------- transpose + convert: dst[c][r] = (bf16)src[r][c] ----------------
__global__ __launch_bounds__(256) void twc_kernel(const void* __restrict__ src,
                                                  u16* __restrict__ dst, int sstride,
                                                  int dstride, size_t soff,
                                                  const int* __restrict__ flag) {
  __shared__ __align__(16) u16 tile[64][72];
  const bool f32 = flag[0] == 0;
  const int r0 = blockIdx.y * 64, c0 = blockIdx.x * 64;
  const int t = threadIdx.x;
  const int rr = t >> 3, cc = t & 7;
#pragma unroll
  for (int i = 0; i < 2; ++i) {
    int row = rr + i * 32;
    size_t idx = (size_t)(r0 + row) * sstride + c0 + cc * 8 + soff;
    if (f32) {
      const f32x4* s = (const f32x4*)((const float*)src + idx);
      f32x4 a = s[0], b = s[1];
      union { u16 t16[8]; u32x4 v; } u_;
#pragma unroll
      for (int j = 0; j < 4; ++j) { u_.t16[j] = f2bf(a[j]); u_.t16[4 + j] = f2bf(b[j]); }
      *(u32x4*)(&tile[row][cc * 8]) = u_.v;
    } else {
      *(u32x4*)(&tile[row][cc * 8]) = *(const u32x4*)((const u16*)src + idx);
    }
  }
  __syncthreads();
  u16* d = dst + (size_t)c0 * dstride + r0;
#pragma unroll
  for (int i = 0; i < 2; ++i) {
    int n = rr + i * 32;
    union { u16 t16[8]; u32x4 v; } u_;
#pragma unroll
    for (int j = 0; j < 8; ++j) u_.t16[j] = tile[cc * 8 + j][n];
    *(u32x4*)(d + (size_t)n * dstride + cc * 8) = u_.v;
  }
}

// ---------------- GEMM: C(MxN) = A(MxK) * Bt(NxK)^T, fused epilogues ----------------
// OUTFLEX: store dtype follows input flag (fp32 world -> float out). moff offsets
// both the C-store row index and the residual-read row index (for split-M).
enum { EP_NONE = 0, EP_SCALE = 1, EP_RES = 2, EP_GELU = 3, EP_BIASRES = 4, EP_VT = 5 };

template <int EPI, bool RESRAW, bool OUTFLEX>
__global__ __launch_bounds__(256, 2) void gemm_bt(const u16* __restrict__ A,
                                                  const u16* __restrict__ Bt,
                                                  void* __restrict__ Cv, int M, int N,
                                                  int K, int moff,
                                                  const void* __restrict__ bias,
                                                  int boff, const void* __restrict__ res,
                                                  const int* __restrict__ flag,
                                                  float scale) {
  __shared__ __align__(16) u16 lds[2 * 128 * 64];  // A tile | B tile, XOR-swizzled
  const int t = threadIdx.x;
  const int w = t >> 6, L = t & 63;
  const int quad = L >> 4, l16 = L & 15;
  const int m0 = blockIdx.y * 128, n0 = blockIdx.x * 128;
  const int wm = (w >> 1) * 64, wn = (w & 1) * 64;
  const int srow = L >> 3;
  const int sc = (L & 7) ^ srow;  // logical source chunk for swizzled store
  const int spc = L & 7;          // physical dest chunk (lane-contiguous for DMA)

  f32x4 acc[4][4] = {};
  const u16* Ab = A + (size_t)m0 * K;
  const u16* Bb = Bt + (size_t)n0 * K;

  for (int kt = 0; kt < K; kt += 64) {
#pragma unroll
    for (int r = 0; r < 4; ++r) {
      int row = r * 32 + w * 8 + srow;
      async16(Ab + (size_t)row * K + kt + sc * 8, &lds[row * 64 + spc * 8]);
    }
#pragma unroll
    for (int r = 0; r < 4; ++r) {
      int row = r * 32 + w * 8 + srow;
      async16(Bb + (size_t)row * K + kt + sc * 8, &lds[8192 + row * 64 + spc * 8]);
    }
    __syncthreads();
#pragma unroll
    for (int ks = 0; ks < 2; ++ks) {
      bf16x8 af[4], bfr[4];
#pragma unroll
      for (int mt = 0; mt < 4; ++mt) {
        int row = wm + mt * 16 + l16;
        af[mt] = ld8(&lds[row * 64 + (((ks * 4 + quad) ^ (l16 & 7)) * 8)]);
      }
#pragma unroll
      for (int nt = 0; nt < 4; ++nt) {
        int row = wn + nt * 16 + l16;
        bfr[nt] = ld8(&lds[8192 + row * 64 + (((ks * 4 + quad) ^ (l16 & 7)) * 8)]);
      }
#pragma unroll
      for (int mt = 0; mt < 4; ++mt)
#pragma unroll
        for (int nt = 0; nt < 4; ++nt)
          acc[mt][nt] =
              __builtin_amdgcn_mfma_f32_16x16x32_bf16(af[mt], bfr[nt], acc[mt][nt], 0, 0, 0);
    }
    __syncthreads();
  }

  const bool f32 = flag[0] == 0;
#pragma unroll
  for (int mt = 0; mt < 4; ++mt) {
#pragma unroll
    for (int nt = 0; nt < 4; ++nt) {
      int col = n0 + wn + nt * 16 + l16;
      float bv = 0.f;
      if (EPI == EP_GELU || EPI == EP_BIASRES) bv = ldf(bias, (size_t)boff + col, f32);
#pragma unroll
      for (int r = 0; r < 4; ++r) {
        int row = m0 + wm + mt * 16 + quad * 4 + r;
        float v = acc[mt][nt][r];
        if (EPI == EP_SCALE) v *= scale;
        if (EPI == EP_GELU) {
          v += bv;
          v = 0.5f * v * (1.0f + erff(v * 0.70710678118654752f));
        }
        if (EPI == EP_RES || EPI == EP_BIASRES) {
          size_t ri = (size_t)(moff + row) * N + col;
          float rv = RESRAW ? ldf(res, ri, f32) : bf2f(((const u16*)res)[ri]);
          v += rv;
          if (EPI == EP_BIASRES) v += bv;
        }
        if (EPI == EP_VT) {
          // v-proj: store transposed vT[(b*8+h)*128 + d][2048], b=row>>11, n=row&2047
          int bb = row >> 11, n = row & 2047, hh = col >> 7, d = col & 127;
          ((u16*)Cv)[(size_t)((bb * 8 + hh) * 128 + d) * 2048 + n] = f2bf(v);
        } else {
          size_t ci = (size_t)(moff + row) * N + col;
          if (OUTFLEX && f32)
            ((float*)Cv)[ci] = v;
          else
            ((u16*)Cv)[ci] = f2bf(v);
        }
      }
    }
  }
}

// ---------------- Flash differential attention ----------------
// grid 512 = b(2) x h(8) x qtile(32 of 64 rows). 4 waves: comp=w>>1, rowhalf=(w&1)*32.
// LDS (u16): K[2][64][64] @0 | Vt[128][64] @8192 | P/Qstage[4][32][64] @16384
__global__ __launch_bounds__(256, 2) void attn_kernel(
    const u16* __restrict__ q, const u16* __restrict__ k, const u16* __restrict__ vT,
    const float* __restrict__ lamp, const void* __restrict__ subw,
    const int* __restrict__ flag, u16* __restrict__ o) {
  __shared__ __align__(16) u16 lds[24576];
  const int t = threadIdx.x, w = t >> 6, L = t & 63;
  const int quad = L >> 4, l16 = L & 15;
  const int bid = blockIdx.x;
  const int qt = bid & 31, h = (bid >> 5) & 7, b = bid >> 8;
  const int q0 = qt * 64;
  const int comp = w >> 1, rh = (w & 1) * 32;
  const int srow = L >> 3, spc = L & 7, sc = spc ^ srow;

  // stage Q (both comps) into P region, pull A-frags into regs
#pragma unroll
  for (int r = 0; r < 4; ++r) {
    int row = r * 32 + w * 8 + srow;  // 0..127 : comp=row>>6, qrow=row&63
    int c_ = row >> 6, qr = row & 63;
    async16(q + ((size_t)(b * 2048 + q0 + qr) * 1024 + (2 * h + c_) * 64 + sc * 8),
            &lds[16384 + row * 64 + spc * 8]);
  }
  __syncthreads();
  bf16x8 qf[2][2];
#pragma unroll
  for (int mt = 0; mt < 2; ++mt)
#pragma unroll
    for (int ks = 0; ks < 2; ++ks) {
      int row = rh + mt * 16 + l16;
      qf[mt][ks] =
          ld8(&lds[16384 + comp * 4096 + row * 64 + (((ks * 4 + quad) ^ (l16 & 7)) * 8)]);
    }
  __syncthreads();

  float mst[2][4], lst[2][4];
#pragma unroll
  for (int mt = 0; mt < 2; ++mt)
#pragma unroll
    for (int r = 0; r < 4; ++r) { mst[mt][r] = -3.0e38f; lst[mt][r] = 0.f; }
  f32x4 oacc[2][8] = {};

  const u16* vb = vT + (size_t)(b * 8 + h) * (128 * 2048);
  const int pbase = 16384 + w * 2048;

  for (int kt = 0; kt < 2048; kt += 64) {
#pragma unroll
    for (int r = 0; r < 4; ++r) {
      int row = r * 32 + w * 8 + srow;  // comp=row>>6, key=row&63
      int c_ = row >> 6, key = row & 63;
      async16(k + ((size_t)(b * 2048 + kt + key) * 1024 + (2 * h + c_) * 64 + sc * 8),
              &lds[row * 64 + spc * 8]);
    }
#pragma unroll
    for (int r = 0; r < 4; ++r) {
      int dim = r * 32 + w * 8 + srow;  // 0..127
      async16(vb + (size_t)dim * 2048 + kt + sc * 8, &lds[8192 + dim * 64 + spc * 8]);
    }
    __syncthreads();

    // S = Q * Ktile^T for own comp (32 q rows per wave)
    f32x4 s[2][4] = {};
#pragma unroll
    for (int ks = 0; ks < 2; ++ks) {
      bf16x8 kf[4];
#pragma unroll
      for (int nt = 0; nt < 4; ++nt) {
        int row = nt * 16 + l16;
        kf[nt] = ld8(&lds[comp * 4096 + row * 64 + (((ks * 4 + quad) ^ (l16 & 7)) * 8)]);
      }
#pragma unroll
      for (int mt = 0; mt < 2; ++mt)
#pragma unroll
        for (int nt = 0; nt < 4; ++nt)
          s[mt][nt] = __builtin_amdgcn_mfma_f32_16x16x32_bf16(qf[mt][ks], kf[nt], s[mt][nt], 0, 0, 0);
    }

    // online softmax per owned row
#pragma unroll
    for (int mt = 0; mt < 2; ++mt) {
#pragma unroll
      for (int r = 0; r < 4; ++r) {
        float mx = fmaxf(fmaxf(s[mt][0][r], s[mt][1][r]), fmaxf(s[mt][2][r], s[mt][3][r]));
        mx = fmaxf(mx, __shfl_xor(mx, 1));
        mx = fmaxf(mx, __shfl_xor(mx, 2));
        mx = fmaxf(mx, __shfl_xor(mx, 4));
        mx = fmaxf(mx, __shfl_xor(mx, 8));
        float mnew = fmaxf(mst[mt][r], mx);
        float al = exp2f((mst[mt][r] - mnew) * LOG2E);
        float ps = 0.f;
#pragma unroll
        for (int nt = 0; nt < 4; ++nt) {
          float p = exp2f((s[mt][nt][r] - mnew) * LOG2E);
          s[mt][nt][r] = p;
          ps += p;
        }
        ps += __shfl_xor(ps, 1);
        ps += __shfl_xor(ps, 2);
        ps += __shfl_xor(ps, 4);
        ps += __shfl_xor(ps, 8);
        lst[mt][r] = lst[mt][r] * al + ps;
        mst[mt][r] = mnew;
#pragma unroll
        for (int nt = 0; nt < 8; ++nt) oacc[mt][nt][r] *= al;
      }
    }

    // P (C-layout) -> LDS (A-layout readable), wave-private region
#pragma unroll
    for (int mt = 0; mt < 2; ++mt)
#pragma unroll
      for (int nt = 0; nt < 4; ++nt)
#pragma unroll
        for (int r = 0; r < 4; ++r) {
          int prow = mt * 16 + quad * 4 + r;
          int key = nt * 16 + l16;
          int pc = (key >> 3) ^ (prow & 7);
          lds[pbase + prow * 64 + pc * 8 + (key & 7)] = f2bf(s[mt][nt][r]);
        }
    __syncthreads();  // order P stores before P loads

    // O += P * Vtile
#pragma unroll
    for (int ks = 0; ks < 2; ++ks) {
      bf16x8 pf[2];
#pragma unroll
      for (int mt = 0; mt < 2; ++mt) {
        int row = mt * 16 + l16;
        pf[mt] = ld8(&lds[pbase + row * 64 + (((ks * 4 + quad) ^ (l16 & 7)) * 8)]);
      }
#pragma unroll
      for (int nt = 0; nt < 8; ++nt) {
        int dim = nt * 16 + l16;
        bf16x8 vf = ld8(&lds[8192 + dim * 64 + (((ks * 4 + quad) ^ (l16 & 7)) * 8)]);
#pragma unroll
        for (int mt = 0; mt < 2; ++mt)
          oacc[mt][nt] = __builtin_amdgcn_mfma_f32_16x16x32_bf16(pf[mt], vf, oacc[mt][nt], 0, 0, 0);
      }
    }
    __syncthreads();
  }

  // normalize by l
#pragma unroll
  for (int mt = 0; mt < 2; ++mt)
#pragma unroll
    for (int r = 0; r < 4; ++r) {
      float inv = 1.0f / lst[mt][r];
#pragma unroll
      for (int nt = 0; nt < 8; ++nt) oacc[mt][nt][r] *= inv;
    }

  // combine: comp1 waves dump normalized O2 (fp32) to LDS; comp0 diff+RMS+store
  float* cb = (float*)lds;  // 64 rows x 132 floats
  if (comp == 1) {
#pragma unroll
    for (int mt = 0; mt < 2; ++mt)
#pragma unroll
      for (int nt = 0; nt < 8; ++nt)
#pragma unroll
        for (int r = 0; r < 4; ++r) {
          int rowc = rh + mt * 16 + quad * 4 + r;
          cb[rowc * 132 + nt * 16 + l16] = oacc[mt][nt][r];
        }
  }
  __syncthreads();
  if (comp == 0) {
    const bool f32 = flag[0] == 0;
    float lam = lamp[0];
#pragma unroll
    for (int mt = 0; mt < 2; ++mt)
#pragma unroll
      for (int r = 0; r < 4; ++r) {
        int rowc = rh + mt * 16 + quad * 4 + r;
        float dv[8];
        float sq = 0.f;
#pragma unroll
        for (int nt = 0; nt < 8; ++nt) {
          float d = oacc[mt][nt][r] - lam * cb[rowc * 132 + nt * 16 + l16];
          dv[nt] = d;
          sq += d * d;
        }
        sq += __shfl_xor(sq, 1);
        sq += __shfl_xor(sq, 2);
        sq += __shfl_xor(sq, 4);
        sq += __shfl_xor(sq, 8);
        float rms = rsqrtf(sq * (1.0f / 128.0f) + 1e-5f);
        size_t rowg = (size_t)(b * 2048 + q0 + rowc) * 1024 + h * 128;
#pragma unroll
        for (int nt = 0; nt < 8; ++nt) {
          int dim = nt * 16 + l16;
          o[rowg + dim] = f2bf(dv[nt] * rms * ldf(subw, dim, f32) * ONE_MINUS_LAM_INIT);
        }
      }
  }
}

// ---------------- host ----------------
extern "C" void kernel_launch(void* const* d_in, const int* in_sizes, int n_in,
                              void* d_out, int out_size, void* d_ws, size_t ws_size,
                              hipStream_t stream) {
  (void)in_sizes; (void)n_in; (void)out_size; (void)ws_size;
  const void* x = d_in[0];
  const void* ln1w = d_in[1];
  const void* ln1b = d_in[2];
  const void* Wq = d_in[3];
  const void* Wk = d_in[4];
  const void* Wv = d_in[5];
  const void* Wo = d_in[6];
  const void* lq1 = d_in[7];
  const void* lk1 = d_in[8];
  const void* lq2 = d_in[9];
  const void* lk2 = d_in[10];
  const void* subw = d_in[11];
  const void* ln2w = d_in[12];
  const void* ln2b = d_in[13];
  const void* W1 = d_in[14];
  const void* b1 = d_in[15];
  const void* W2 = d_in[16];
  const void* b2 = d_in[17];

  char* ws = (char*)d_ws;
  const size_t MB = 1u << 20;
  u16* A = (u16*)ws;               // h1 -> ob -> h2
  u16* B = (u16*)(ws + 8 * MB);    // q -> g rows 0..2047
  u16* C = (u16*)(ws + 16 * MB);   // k -> x2
  u16* D = (u16*)(ws + 24 * MB);   // vT -> W1Th | W2Th
  u16* E = (u16*)(ws + 32 * MB);   // WqT|WkT|WvT|WoT -> g rows 2048..4095
  float* lam = (float*)(ws + 40 * MB);
  int* flag = (int*)(ws + 40 * MB + 64);
  u16* WqT = E;
  u16* WkT = E + 1048576;
  u16* WvT = E + 2097152;
  u16* WoT = E + 3145728;
  u16* W1Th = D;
  u16* W2Th = D + 2097152;
  u16* x2 = C;
  const size_t HALF = (size_t)2048 * 1024;  // elems, for bf16 ws pointers only

  detect_kernel<<<dim3(1), dim3(64), 0, stream>>>((const u32*)x, flag);
  lam_kernel<<<dim3(1), dim3(64), 0, stream>>>(lq1, lk1, lq2, lk2, flag, lam);
  ln_kernel<true><<<dim3(1024), dim3(256), 0, stream>>>(x, ln1w, ln1b, flag, A);

  twc_kernel<<<dim3(16, 16), dim3(256), 0, stream>>>(Wq, WqT, 1024, 1024, 0, flag);
  twc_kernel<<<dim3(16, 16), dim3(256), 0, stream>>>(Wk, WkT, 1024, 1024, 0, flag);
  twc_kernel<<<dim3(16, 16), dim3(256), 0, stream>>>(Wv, WvT, 1024, 1024, 0, flag);
  twc_kernel<<<dim3(16, 16), dim3(256), 0, stream>>>(Wo, WoT, 1024, 1024, 0, flag);

  gemm_bt<EP_SCALE, false, false><<<dim3(8, 32), dim3(256), 0, stream>>>(
      A, WqT, B, 4096, 1024, 1024, 0, nullptr, 0, nullptr, flag, 0.125f);
  gemm_bt<EP_NONE, false, false><<<dim3(8, 32), dim3(256), 0, stream>>>(
      A, WkT, C, 4096, 1024, 1024, 0, nullptr, 0, nullptr, flag, 1.f);
  gemm_bt<EP_VT, false, false><<<dim3(8, 32), dim3(256), 0, stream>>>(
      A, WvT, D, 4096, 1024, 1024, 0, nullptr, 0, nullptr, flag, 1.f);

  attn_kernel<<<dim3(512), dim3(256), 0, stream>>>(B, C, D, lam, subw, flag, A);

  // x2(bf16 ws) = attn-out @ Wo + x(raw)
  gemm_bt<EP_RES, true, false><<<dim3(8, 32), dim3(256), 0, stream>>>(
      A, WoT, C, 4096, 1024, 1024, 0, nullptr, 0, x, flag, 1.f);
  ln_kernel<false><<<dim3(1024), dim3(256), 0, stream>>>(C, ln2w, ln2b, flag, A);

  // FFN: two FF-column halves; within each, M split 2x2048 (g spans slots B and E).
  // Output written in INPUT dtype (OUTFLEX): fp32 world -> float stores.
  for (int hh = 0; hh < 2; ++hh) {
    twc_kernel<<<dim3(32, 16), dim3(256), 0, stream>>>(W1, W1Th, 4096, 1024,
                                                       (size_t)hh * 2048, flag);
    twc_kernel<<<dim3(16, 32), dim3(256), 0, stream>>>(W2, W2Th, 1024, 2048,
                                                       (size_t)hh * 2048 * 1024, flag);
    gemm_bt<EP_GELU, false, false><<<dim3(16, 16), dim3(256), 0, stream>>>(
        A, W1Th, B, 2048, 2048, 1024, 0, b1, hh * 2048, nullptr, flag, 1.f);
    gemm_bt<EP_GELU, false, false><<<dim3(16, 16), dim3(256), 0, stream>>>(
        A + HALF, W1Th, E, 2048, 2048, 1024, 0, b1, hh * 2048, nullptr, flag, 1.f);
    if (hh == 0) {
      gemm_bt<EP_BIASRES, false, true><<<dim3(8, 16), dim3(256), 0, stream>>>(
          B, W2Th, d_out, 2048, 1024, 2048, 0, b2, 0, x2, flag, 1.f);
      gemm_bt<EP_BIASRES, false, true><<<dim3(8, 16), dim3(256), 0, stream>>>(
          E, W2Th, d_out, 2048, 1024, 2048, 2048, b2, 0, x2, flag, 1.f);
    } else {
      gemm_bt<EP_RES, true, true><<<dim3(8, 16), dim3(256), 0, stream>>>(
          B, W2Th, d_out, 2048, 1024, 2048, 0, nullptr, 0, d_out, flag, 1.f);
      gemm_bt<EP_RES, true, true><<<dim3(8, 16), dim3(256), 0, stream>>>(
          E, W2Th, d_out, 2048, 1024, 2048, 2048, nullptr, 0, d_out, flag, 1.f);
    }
  }
}

// Round 7
// 569.602 us; speedup vs baseline: 1.3733x; 1.3733x over previous
//
#include <hip/hip_runtime.h>

// DiffAttnLayer: B=2,N=2048,EMB=1024,H=8,HD=64,FF=4096.
// Inputs fp32 (runtime-detected); output dtype follows input dtype.
// R7 = R6 GEMM re-grid (fused QKV, TM=64/128, full-M FFN) + R5 attention
// (known-good: online softmax, VALU l, 3-barrier staging) -- bisection round.
// Workspace: 5 x 8MB slots + scalars @40MB:
//  A: h1 -> ob -> h2        B: q -> g(lo)      C: k -> g(hi)
//  D: vT -> WoT -> W1Th|W2Th                   E: WqT|WkT|WvT -> x2

typedef unsigned short u16;
typedef unsigned int u32;
typedef __attribute__((ext_vector_type(8))) __bf16 bf16x8;
typedef __attribute__((ext_vector_type(4))) float f32x4;
typedef __attribute__((ext_vector_type(4))) u32 u32x4;

#define LOG2E 1.4426950408889634f
#define LAM_INIT 0.355509068f
#define ONE_MINUS_LAM_INIT 0.644490932f

__device__ __forceinline__ float bf2f(u16 x) {
  u32 u = ((u32)x) << 16;
  return __builtin_bit_cast(float, u);
}
__device__ __forceinline__ u16 f2bf(float f) {
  u32 u = __builtin_bit_cast(u32, f);
  u32 r = (u + 0x7FFFu + ((u >> 16) & 1u)) >> 16;
  return (u16)r;
}
__device__ __forceinline__ float ldf(const void* p, size_t i, bool f32) {
  return f32 ? ((const float*)p)[i] : bf2f(((const u16*)p)[i]);
}
// global -> LDS async DMA, 16B/lane; LDS dest = wave-uniform base + lane*16.
__device__ __forceinline__ void async16(const u16* g, u16* l) {
  __builtin_amdgcn_global_load_lds((const __attribute__((address_space(1))) u32*)g,
                                   (__attribute__((address_space(3))) u32*)l, 16, 0, 0);
}
__device__ __forceinline__ bf16x8 ld8(const u16* p) { return *(const bf16x8*)p; }

// ---------------- input-dtype detector (1 = bf16, 0 = fp32) ----------------
__global__ void detect_kernel(const u32* x, int* flag) {
  int e = (x[threadIdx.x] >> 7) & 0xFF;
  unsigned long long m = __ballot(e >= 90 && e <= 150);
  if (threadIdx.x == 0) flag[0] = (__popcll(m) >= 40) ? 1 : 0;
}

// ---------------- lambda ----------------
__global__ void lam_kernel(const void* lq1, const void* lk1, const void* lq2,
                           const void* lk2, const int* flag, float* out) {
  const bool f32 = flag[0] == 0;
  int L = threadIdx.x;
  float a = ldf(lq1, L, f32) * ldf(lk1, L, f32);
  float c = ldf(lq2, L, f32) * ldf(lk2, L, f32);
#pragma unroll
  for (int m = 1; m < 64; m <<= 1) { a += __shfl_xor(a, m); c += __shfl_xor(c, m); }
  if (L == 0) out[0] = __expf(a) - __expf(c) + LAM_INIT;
}

// ---------------- LayerNorm over 1024, one wave per row ----------------
__device__ __forceinline__ void unpack8(u32x4 u, float* f) {
#pragma unroll
  for (int i = 0; i < 4; ++i) {
    f[2 * i] = bf2f((u16)(u[i] & 0xffffu));
    f[2 * i + 1] = bf2f((u16)(u[i] >> 16));
  }
}

template <bool XRAW>
__global__ __launch_bounds__(256) void ln_kernel(const void* __restrict__ x,
                                                 const void* __restrict__ w,
                                                 const void* __restrict__ b,
                                                 const int* __restrict__ flag,
                                                 u16* __restrict__ out) {
  const bool f32 = flag[0] == 0;
  const int row = blockIdx.x * 4 + (threadIdx.x >> 6);
  const int L = threadIdx.x & 63;
  float xv[16];
  if (XRAW && f32) {
    const f32x4* xr = (const f32x4*)((const float*)x + (size_t)row * 1024 + L * 16);
#pragma unroll
    for (int i = 0; i < 4; ++i) {
      f32x4 vv = xr[i];
#pragma unroll
      for (int j = 0; j < 4; ++j) xv[i * 4 + j] = vv[j];
    }
  } else {
    const u16* xr = (const u16*)x + (size_t)row * 1024 + L * 16;
    unpack8(*(const u32x4*)xr, xv);
    unpack8(*(const u32x4*)(xr + 8), xv + 8);
  }
  float s = 0.f, sq = 0.f;
#pragma unroll
  for (int i = 0; i < 16; ++i) { s += xv[i]; sq += xv[i] * xv[i]; }
#pragma unroll
  for (int m = 1; m < 64; m <<= 1) { s += __shfl_xor(s, m); sq += __shfl_xor(sq, m); }
  float mean = s * (1.0f / 1024.0f);
  float var = sq * (1.0f / 1024.0f) - mean * mean;
  float rstd = rsqrtf(var + 1e-5f);
  u32 pk[8];
#pragma unroll
  for (int i = 0; i < 8; ++i) {
    float w0 = ldf(w, L * 16 + 2 * i, f32), w1 = ldf(w, L * 16 + 2 * i + 1, f32);
    float b0 = ldf(b, L * 16 + 2 * i, f32), b1v = ldf(b, L * 16 + 2 * i + 1, f32);
    float v0 = (xv[2 * i] - mean) * rstd * w0 + b0;
    float v1 = (xv[2 * i + 1] - mean) * rstd * w1 + b1v;
    pk[i] = (u32)f2bf(v0) | ((u32)f2bf(v1) << 16);
  }
  u32x4 o0 = {pk[0], pk[1], pk[2], pk[3]};
  u32x4 o1 = {pk[4], pk[5], pk[6], pk[7]};
  *(u32x4*)(out + (size_t)row * 1024 + L * 16) = o0;
  *(u32x4*)(out + (size_t)row * 1024 + L * 16 + 8) = o1;
}

// -------- transpose+convert: dst[z][c][r] = (bf16)src_z[r][c], z-multiplexed --------
__global__ __launch_bounds__(256) void twc_kernel(const void* __restrict__ s0,
                                                  const void* __restrict__ s1,
                                                  const void* __restrict__ s2,
                                                  u16* __restrict__ dst, int sstride,
                                                  int dstride, size_t soff, size_t dzoff,
                                                  const int* __restrict__ flag) {
  __shared__ __align__(16) u16 tile[64][72];
  const bool f32 = flag[0] == 0;
  const void* src = blockIdx.z == 0 ? s0 : (blockIdx.z == 1 ? s1 : s2);
  u16* dz = dst + (size_t)blockIdx.z * dzoff;
  const int r0 = blockIdx.y * 64, c0 = blockIdx.x * 64;
  const int t = threadIdx.x;
  const int rr = t >> 3, cc = t & 7;
#pragma unroll
  for (int i = 0; i < 2; ++i) {
    int row = rr + i * 32;
    size_t idx = (size_t)(r0 + row) * sstride + c0 + cc * 8 + soff;
    if (f32) {
      const f32x4* s = (const f32x4*)((const float*)src + idx);
      f32x4 a = s[0], b = s[1];
      union { u16 t16[8]; u32x4 v; } u_;
#pragma unroll
      for (int j = 0; j < 4; ++j) { u_.t16[j] = f2bf(a[j]); u_.t16[4 + j] = f2bf(b[j]); }
      *(u32x4*)(&tile[row][cc * 8]) = u_.v;
    } else {
      *(u32x4*)(&tile[row][cc * 8]) = *(const u32x4*)((const u16*)src + idx);
    }
  }
  __syncthreads();
  u16* d = dz + (size_t)c0 * dstride + r0;
#pragma unroll
  for (int i = 0; i < 2; ++i) {
    int n = rr + i * 32;
    union { u16 t16[8]; u32x4 v; } u_;
#pragma unroll
    for (int j = 0; j < 8; ++j) u_.t16[j] = tile[cc * 8 + j][n];
    *(u32x4*)(d + (size_t)n * dstride + cc * 8) = u_.v;
  }
}

// ------------- GEMM: C(MxN) = A(MxK) * Bt(NxK)^T, tile TM x 128 --------------
enum { EP_NONE = 0, EP_RES = 2, EP_GELU = 3, EP_BIASRES = 4, EP_QKV = 5 };

template <int TM, int EPI, bool RESRAW, bool OUTFLEX>
__global__ __launch_bounds__(256, 2) void gemm_bt(
    const u16* __restrict__ A, const u16* __restrict__ Bt, void* __restrict__ Cv,
    int M, int N, int K, const void* __restrict__ bias, int boff,
    const void* __restrict__ res, const int* __restrict__ flag,
    u16* __restrict__ kout, u16* __restrict__ vtout) {
  constexpr int MT = TM / 32;  // acc tiles per wave in M
  __shared__ __align__(16) u16 lds[TM * 64 + 128 * 64];
  const int t = threadIdx.x;
  const int w = t >> 6, L = t & 63;
  const int quad = L >> 4, l16 = L & 15;
  const int m0 = blockIdx.y * TM, n0 = blockIdx.x * 128;
  const int wm = (TM == 128) ? (w >> 1) * 64 : (w & 1) * 32;
  const int wn = (TM == 128) ? (w & 1) * 64 : (w >> 1) * 64;
  const int srow = L >> 3, spc = L & 7;
  const int sc = spc ^ srow;
  constexpr int BBASE = TM * 64;

  f32x4 acc[MT][4] = {};
  const u16* Ab = A + (size_t)m0 * K;
  const u16* Bb = Bt + (size_t)n0 * K;

  for (int kt = 0; kt < K; kt += 64) {
#pragma unroll
    for (int r = 0; r < TM / 32; ++r) {
      int row = r * 32 + w * 8 + srow;
      async16(Ab + (size_t)row * K + kt + sc * 8, &lds[row * 64 + spc * 8]);
    }
#pragma unroll
    for (int r = 0; r < 4; ++r) {
      int row = r * 32 + w * 8 + srow;
      async16(Bb + (size_t)row * K + kt + sc * 8, &lds[BBASE + row * 64 + spc * 8]);
    }
    __syncthreads();
#pragma unroll
    for (int ks = 0; ks < 2; ++ks) {
      bf16x8 af[MT], bfr[4];
#pragma unroll
      for (int mt = 0; mt < MT; ++mt) {
        int row = wm + mt * 16 + l16;
        af[mt] = ld8(&lds[row * 64 + (((ks * 4 + quad) ^ (l16 & 7)) * 8)]);
      }
#pragma unroll
      for (int nt = 0; nt < 4; ++nt) {
        int row = wn + nt * 16 + l16;
        bfr[nt] = ld8(&lds[BBASE + row * 64 + (((ks * 4 + quad) ^ (l16 & 7)) * 8)]);
      }
#pragma unroll
      for (int mt = 0; mt < MT; ++mt)
#pragma unroll
        for (int nt = 0; nt < 4; ++nt)
          acc[mt][nt] =
              __builtin_amdgcn_mfma_f32_16x16x32_bf16(af[mt], bfr[nt], acc[mt][nt], 0, 0, 0);
    }
    __syncthreads();
  }

  const bool f32 = flag[0] == 0;
#pragma unroll
  for (int mt = 0; mt < MT; ++mt) {
#pragma unroll
    for (int nt = 0; nt < 4; ++nt) {
      int col = n0 + wn + nt * 16 + l16;
      float bv = 0.f;
      if (EPI == EP_GELU || EPI == EP_BIASRES) bv = ldf(bias, (size_t)boff + col, f32);
#pragma unroll
      for (int r = 0; r < 4; ++r) {
        int row = m0 + wm + mt * 16 + quad * 4 + r;
        float v = acc[mt][nt][r];
        if (EPI == EP_GELU) {
          v += bv;
          v = 0.5f * v * (1.0f + erff(v * 0.70710678118654752f));
        }
        if (EPI == EP_RES || EPI == EP_BIASRES) {
          size_t ri = (size_t)row * N + col;
          float rv = RESRAW ? ldf(res, ri, f32) : bf2f(((const u16*)res)[ri]);
          v += rv;
          if (EPI == EP_BIASRES) v += bv;
        }
        if (EPI == EP_QKV) {
          if (col < 1024) {
            ((u16*)Cv)[(size_t)row * 1024 + col] = f2bf(v * 0.125f);  // q, pre-scaled
          } else if (col < 2048) {
            kout[(size_t)row * 1024 + (col - 1024)] = f2bf(v);  // k
          } else {  // v stored transposed: vT[(b*8+h)*128+d][2048]
            int c2 = col - 2048;
            int bb = row >> 11, n = row & 2047, hh = c2 >> 7, d = c2 & 127;
            vtout[(size_t)((bb * 8 + hh) * 128 + d) * 2048 + n] = f2bf(v);
          }
        } else {
          size_t ci = (size_t)row * N + col;
          if (OUTFLEX && f32)
            ((float*)Cv)[ci] = v;
          else
            ((u16*)Cv)[ci] = f2bf(v);
        }
      }
    }
  }
}

// ---------------- Flash differential attention (R5 known-good version) ----------------
// grid 512 = b(2) x h(8) x qtile(32 of 64 rows). 4 waves: comp=w>>1, rowhalf=(w&1)*32.
// LDS (u16): K[2][64][64] @0 | Vt[128][64] @8192 | P/Qstage[4][32][64] @16384
__global__ __launch_bounds__(256, 2) void attn_kernel(
    const u16* __restrict__ q, const u16* __restrict__ k, const u16* __restrict__ vT,
    const float* __restrict__ lamp, const void* __restrict__ subw,
    const int* __restrict__ flag, u16* __restrict__ o) {
  __shared__ __align__(16) u16 lds[24576];
  const int t = threadIdx.x, w = t >> 6, L = t & 63;
  const int quad = L >> 4, l16 = L & 15;
  const int bid = blockIdx.x;
  const int qt = bid & 31, h = (bid >> 5) & 7, b = bid >> 8;
  const int q0 = qt * 64;
  const int comp = w >> 1, rh = (w & 1) * 32;
  const int srow = L >> 3, spc = L & 7, sc = spc ^ srow;

  // stage Q (both comps) into P region, pull A-frags into regs
#pragma unroll
  for (int r = 0; r < 4; ++r) {
    int row = r * 32 + w * 8 + srow;  // 0..127 : comp=row>>6, qrow=row&63
    int c_ = row >> 6, qr = row & 63;
    async16(q + ((size_t)(b * 2048 + q0 + qr) * 1024 + (2 * h + c_) * 64 + sc * 8),
            &lds[16384 + row * 64 + spc * 8]);
  }
  __syncthreads();
  bf16x8 qf[2][2];
#pragma unroll
  for (int mt = 0; mt < 2; ++mt)
#pragma unroll
    for (int ks = 0; ks < 2; ++ks) {
      int row = rh + mt * 16 + l16;
      qf[mt][ks] =
          ld8(&lds[16384 + comp * 4096 + row * 64 + (((ks * 4 + quad) ^ (l16 & 7)) * 8)]);
    }
  __syncthreads();

  float mst[2][4], lst[2][4];
#pragma unroll
  for (int mt = 0; mt < 2; ++mt)
#pragma unroll
    for (int r = 0; r < 4; ++r) { mst[mt][r] = -3.0e38f; lst[mt][r] = 0.f; }
  f32x4 oacc[2][8] = {};

  const u16* vb = vT + (size_t)(b * 8 + h) * (128 * 2048);
  const int pbase = 16384 + w * 2048;

  for (int kt = 0; kt < 2048; kt += 64) {
#pragma unroll
    for (int r = 0; r < 4; ++r) {
      int row = r * 32 + w * 8 + srow;  // comp=row>>6, key=row&63
      int c_ = row >> 6, key = row & 63;
      async16(k + ((size_t)(b * 2048 + kt + key) * 1024 + (2 * h + c_) * 64 + sc * 8),
              &lds[row * 64 + spc * 8]);
    }
#pragma unroll
    for (int r = 0; r < 4; ++r) {
      int dim = r * 32 + w * 8 + srow;  // 0..127
      async16(vb + (size_t)dim * 2048 + kt + sc * 8, &lds[8192 + dim * 64 + spc * 8]);
    }
    __syncthreads();

    // S = Q * Ktile^T for own comp (32 q rows per wave)
    f32x4 s[2][4] = {};
#pragma unroll
    for (int ks = 0; ks < 2; ++ks) {
      bf16x8 kf[4];
#pragma unroll
      for (int nt = 0; nt < 4; ++nt) {
        int row = nt * 16 + l16;
        kf[nt] = ld8(&lds[comp * 4096 + row * 64 + (((ks * 4 + quad) ^ (l16 & 7)) * 8)]);
      }
#pragma unroll
      for (int mt = 0; mt < 2; ++mt)
#pragma unroll
        for (int nt = 0; nt < 4; ++nt)
          s[mt][nt] = __builtin_amdgcn_mfma_f32_16x16x32_bf16(qf[mt][ks], kf[nt], s[mt][nt], 0, 0, 0);
    }

    // online softmax per owned row
#pragma unroll
    for (int mt = 0; mt < 2; ++mt) {
#pragma unroll
      for (int r = 0; r < 4; ++r) {
        float mx = fmaxf(fmaxf(s[mt][0][r], s[mt][1][r]), fmaxf(s[mt][2][r], s[mt][3][r]));
        mx = fmaxf(mx, __shfl_xor(mx, 1));
        mx = fmaxf(mx, __shfl_xor(mx, 2));
        mx = fmaxf(mx, __shfl_xor(mx, 4));
        mx = fmaxf(mx, __shfl_xor(mx, 8));
        float mnew = fmaxf(mst[mt][r], mx);
        float al = exp2f((mst[mt][r] - mnew) * LOG2E);
        float ps = 0.f;
#pragma unroll
        for (int nt = 0; nt < 4; ++nt) {
          float p = exp2f((s[mt][nt][r] - mnew) * LOG2E);
          s[mt][nt][r] = p;
          ps += p;
        }
        ps += __shfl_xor(ps, 1);
        ps += __shfl_xor(ps, 2);
        ps += __shfl_xor(ps, 4);
        ps += __shfl_xor(ps, 8);
        lst[mt][r] = lst[mt][r] * al + ps;
        mst[mt][r] = mnew;
#pragma unroll
        for (int nt = 0; nt < 8; ++nt) oacc[mt][nt][r] *= al;
      }
    }

    // P (C-layout) -> LDS (A-layout readable), wave-private region
#pragma unroll
    for (int mt = 0; mt < 2; ++mt)
#pragma unroll
      for (int nt = 0; nt < 4; ++nt)
#pragma unroll
        for (int r = 0; r < 4; ++r) {
          int prow = mt * 16 + quad * 4 + r;
          int key = nt * 16 + l16;
          int pc = (key >> 3) ^ (prow & 7);
          lds[pbase + prow * 64 + pc * 8 + (key & 7)] = f2bf(s[mt][nt][r]);
        }
    __syncthreads();  // order P stores before P loads

    // O += P * Vtile
#pragma unroll
    for (int ks = 0; ks < 2; ++ks) {
      bf16x8 pf[2];
#pragma unroll
      for (int mt = 0; mt < 2; ++mt) {
        int row = mt * 16 + l16;
        pf[mt] = ld8(&lds[pbase + row * 64 + (((ks * 4 + quad) ^ (l16 & 7)) * 8)]);
      }
#pragma unroll
      for (int nt = 0; nt < 8; ++nt) {
        int dim = nt * 16 + l16;
        bf16x8 vf = ld8(&lds[8192 + dim * 64 + (((ks * 4 + quad) ^ (l16 & 7)) * 8)]);
#pragma unroll
        for (int mt = 0; mt < 2; ++mt)
          oacc[mt][nt] = __builtin_amdgcn_mfma_f32_16x16x32_bf16(pf[mt], vf, oacc[mt][nt], 0, 0, 0);
      }
    }
    __syncthreads();
  }

  // normalize by l
#pragma unroll
  for (int mt = 0; mt < 2; ++mt)
#pragma unroll
    for (int r = 0; r < 4; ++r) {
      float inv = 1.0f / lst[mt][r];
#pragma unroll
      for (int nt = 0; nt < 8; ++nt) oacc[mt][nt][r] *= inv;
    }

  // combine: comp1 waves dump normalized O2 (fp32) to LDS; comp0 diff+RMS+store
  float* cb = (float*)lds;  // 64 rows x 132 floats
  if (comp == 1) {
#pragma unroll
    for (int mt = 0; mt < 2; ++mt)
#pragma unroll
      for (int nt = 0; nt < 8; ++nt)
#pragma unroll
        for (int r = 0; r < 4; ++r) {
          int rowc = rh + mt * 16 + quad * 4 + r;
          cb[rowc * 132 + nt * 16 + l16] = oacc[mt][nt][r];
        }
  }
  __syncthreads();
  if (comp == 0) {
    const bool f32 = flag[0] == 0;
    float lam = lamp[0];
#pragma unroll
    for (int mt = 0; mt < 2; ++mt)
#pragma unroll
      for (int r = 0; r < 4; ++r) {
        int rowc = rh + mt * 16 + quad * 4 + r;
        float dv[8];
        float sq = 0.f;
#pragma unroll
        for (int nt = 0; nt < 8; ++nt) {
          float d = oacc[mt][nt][r] - lam * cb[rowc * 132 + nt * 16 + l16];
          dv[nt] = d;
          sq += d * d;
        }
        sq += __shfl_xor(sq, 1);
        sq += __shfl_xor(sq, 2);
        sq += __shfl_xor(sq, 4);
        sq += __shfl_xor(sq, 8);
        float rms = rsqrtf(sq * (1.0f / 128.0f) + 1e-5f);
        size_t rowg = (size_t)(b * 2048 + q0 + rowc) * 1024 + h * 128;
#pragma unroll
        for (int nt = 0; nt < 8; ++nt) {
          int dim = nt * 16 + l16;
          o[rowg + dim] = f2bf(dv[nt] * rms * ldf(subw, dim, f32) * ONE_MINUS_LAM_INIT);
        }
      }
  }
}

// ---------------- host ----------------
extern "C" void kernel_launch(void* const* d_in, const int* in_sizes, int n_in,
                              void* d_out, int out_size, void* d_ws, size_t ws_size,
                              hipStream_t stream) {
  (void)in_sizes; (void)n_in; (void)out_size; (void)ws_size;
  const void* x = d_in[0];
  const void* ln1w = d_in[1];
  const void* ln1b = d_in[2];
  const void* Wq = d_in[3];
  const void* Wk = d_in[4];
  const void* Wv = d_in[5];
  const void* Wo = d_in[6];
  const void* lq1 = d_in[7];
  const void* lk1 = d_in[8];
  const void* lq2 = d_in[9];
  const void* lk2 = d_in[10];
  const void* subw = d_in[11];
  const void* ln2w = d_in[12];
  const void* ln2b = d_in[13];
  const void* W1 = d_in[14];
  const void* b1 = d_in[15];
  const void* W2 = d_in[16];
  const void* b2 = d_in[17];

  char* ws = (char*)d_ws;
  const size_t MB = 1u << 20;
  u16* A = (u16*)ws;               // h1 -> ob -> h2
  u16* B = (u16*)(ws + 8 * MB);    // q -> g (16MB contiguous over B+C)
  u16* C = (u16*)(ws + 16 * MB);   // k -> g(hi)
  u16* D = (u16*)(ws + 24 * MB);   // vT -> WoT -> W1Th|W2Th
  u16* E = (u16*)(ws + 32 * MB);   // WqT|WkT|WvT -> x2
  float* lam = (float*)(ws + 40 * MB);
  int* flag = (int*)(ws + 40 * MB + 64);
  u16* W2Th = D + 2097152;

  detect_kernel<<<dim3(1), dim3(64), 0, stream>>>((const u32*)x, flag);
  lam_kernel<<<dim3(1), dim3(64), 0, stream>>>(lq1, lk1, lq2, lk2, flag, lam);
  ln_kernel<true><<<dim3(1024), dim3(256), 0, stream>>>(x, ln1w, ln1b, flag, A);

  // Wq|Wk|Wv -> E concatenated n-major (3072 x 1024)
  twc_kernel<<<dim3(16, 16, 3), dim3(256), 0, stream>>>(Wq, Wk, Wv, E, 1024, 1024, 0,
                                                        1048576, flag);
  // fused q/k/v projection: q->B (pre-scaled), k->C, vT->D
  gemm_bt<64, EP_QKV, false, false><<<dim3(24, 64), dim3(256), 0, stream>>>(
      A, E, B, 4096, 3072, 1024, nullptr, 0, nullptr, flag, C, D);

  attn_kernel<<<dim3(512), dim3(256), 0, stream>>>(B, C, D, lam, subw, flag, A);

  // WoT -> D (vT dead); x2(bf16) = ob @ Wo + x -> E (Wq..WvT dead)
  twc_kernel<<<dim3(16, 16, 1), dim3(256), 0, stream>>>(Wo, Wo, Wo, D, 1024, 1024, 0, 0,
                                                        flag);
  gemm_bt<64, EP_RES, true, false><<<dim3(8, 64), dim3(256), 0, stream>>>(
      A, D, E, 4096, 1024, 1024, nullptr, 0, x, flag, nullptr, nullptr);
  ln_kernel<false><<<dim3(1024), dim3(256), 0, stream>>>(E, ln2w, ln2b, flag, A);

  // FFN in two FF-column halves; g = B..C (16MB contiguous), full-M launches
  for (int hh = 0; hh < 2; ++hh) {
    twc_kernel<<<dim3(32, 16, 1), dim3(256), 0, stream>>>(W1, W1, W1, D, 4096, 1024,
                                                          (size_t)hh * 2048, 0, flag);
    twc_kernel<<<dim3(16, 32, 1), dim3(256), 0, stream>>>(
        W2, W2, W2, W2Th, 1024, 2048, (size_t)hh * 2048 * 1024, 0, flag);
    gemm_bt<128, EP_GELU, false, false><<<dim3(16, 32), dim3(256), 0, stream>>>(
        A, D, B, 4096, 2048, 1024, b1, hh * 2048, nullptr, flag, nullptr, nullptr);
    if (hh == 0) {
      gemm_bt<64, EP_BIASRES, false, true><<<dim3(8, 64), dim3(256), 0, stream>>>(
          B, W2Th, d_out, 4096, 1024, 2048, b2, 0, E, flag, nullptr, nullptr);
    } else {
      gemm_bt<64, EP_RES, true, true><<<dim3(8, 64), dim3(256), 0, stream>>>(
          B, W2Th, d_out, 4096, 1024, 2048, nullptr, 0, d_out, flag, nullptr, nullptr);
    }
  }
}

// Round 8
// 550.001 us; speedup vs baseline: 1.4223x; 1.0356x over previous
//
#include <hip/hip_runtime.h>

// DiffAttnLayer: B=2,N=2048,EMB=1024,H=8,HD=64,FF=4096.
// Inputs fp32 (runtime-detected); output dtype follows input dtype.
// R8 = R7 + attention DMA pipelining ONLY (R5 softmax/l numerics kept verbatim;
// bisects R6's regression). 2 barriers/tile: stageK overlaps PV, stageV
// overlaps QK+softmax.
// Workspace: 5 x 8MB slots + scalars @40MB:
//  A: h1 -> ob -> h2        B: q -> g(lo)      C: k -> g(hi)
//  D: vT -> WoT -> W1Th|W2Th                   E: WqT|WkT|WvT -> x2

typedef unsigned short u16;
typedef unsigned int u32;
typedef __attribute__((ext_vector_type(8))) __bf16 bf16x8;
typedef __attribute__((ext_vector_type(4))) float f32x4;
typedef __attribute__((ext_vector_type(4))) u32 u32x4;

#define LOG2E 1.4426950408889634f
#define LAM_INIT 0.355509068f
#define ONE_MINUS_LAM_INIT 0.644490932f

__device__ __forceinline__ float bf2f(u16 x) {
  u32 u = ((u32)x) << 16;
  return __builtin_bit_cast(float, u);
}
__device__ __forceinline__ u16 f2bf(float f) {
  u32 u = __builtin_bit_cast(u32, f);
  u32 r = (u + 0x7FFFu + ((u >> 16) & 1u)) >> 16;
  return (u16)r;
}
__device__ __forceinline__ float ldf(const void* p, size_t i, bool f32) {
  return f32 ? ((const float*)p)[i] : bf2f(((const u16*)p)[i]);
}
// global -> LDS async DMA, 16B/lane; LDS dest = wave-uniform base + lane*16.
__device__ __forceinline__ void async16(const u16* g, u16* l) {
  __builtin_amdgcn_global_load_lds((const __attribute__((address_space(1))) u32*)g,
                                   (__attribute__((address_space(3))) u32*)l, 16, 0, 0);
}
__device__ __forceinline__ bf16x8 ld8(const u16* p) { return *(const bf16x8*)p; }

// ---------------- input-dtype detector (1 = bf16, 0 = fp32) ----------------
__global__ void detect_kernel(const u32* x, int* flag) {
  int e = (x[threadIdx.x] >> 7) & 0xFF;
  unsigned long long m = __ballot(e >= 90 && e <= 150);
  if (threadIdx.x == 0) flag[0] = (__popcll(m) >= 40) ? 1 : 0;
}

// ---------------- lambda ----------------
__global__ void lam_kernel(const void* lq1, const void* lk1, const void* lq2,
                           const void* lk2, const int* flag, float* out) {
  const bool f32 = flag[0] == 0;
  int L = threadIdx.x;
  float a = ldf(lq1, L, f32) * ldf(lk1, L, f32);
  float c = ldf(lq2, L, f32) * ldf(lk2, L, f32);
#pragma unroll
  for (int m = 1; m < 64; m <<= 1) { a += __shfl_xor(a, m); c += __shfl_xor(c, m); }
  if (L == 0) out[0] = __expf(a) - __expf(c) + LAM_INIT;
}

// ---------------- LayerNorm over 1024, one wave per row ----------------
__device__ __forceinline__ void unpack8(u32x4 u, float* f) {
#pragma unroll
  for (int i = 0; i < 4; ++i) {
    f[2 * i] = bf2f((u16)(u[i] & 0xffffu));
    f[2 * i + 1] = bf2f((u16)(u[i] >> 16));
  }
}

template <bool XRAW>
__global__ __launch_bounds__(256) void ln_kernel(const void* __restrict__ x,
                                                 const void* __restrict__ w,
                                                 const void* __restrict__ b,
                                                 const int* __restrict__ flag,
                                                 u16* __restrict__ out) {
  const bool f32 = flag[0] == 0;
  const int row = blockIdx.x * 4 + (threadIdx.x >> 6);
  const int L = threadIdx.x & 63;
  float xv[16];
  if (XRAW && f32) {
    const f32x4* xr = (const f32x4*)((const float*)x + (size_t)row * 1024 + L * 16);
#pragma unroll
    for (int i = 0; i < 4; ++i) {
      f32x4 vv = xr[i];
#pragma unroll
      for (int j = 0; j < 4; ++j) xv[i * 4 + j] = vv[j];
    }
  } else {
    const u16* xr = (const u16*)x + (size_t)row * 1024 + L * 16;
    unpack8(*(const u32x4*)xr, xv);
    unpack8(*(const u32x4*)(xr + 8), xv + 8);
  }
  float s = 0.f, sq = 0.f;
#pragma unroll
  for (int i = 0; i < 16; ++i) { s += xv[i]; sq += xv[i] * xv[i]; }
#pragma unroll
  for (int m = 1; m < 64; m <<= 1) { s += __shfl_xor(s, m); sq += __shfl_xor(sq, m); }
  float mean = s * (1.0f / 1024.0f);
  float var = sq * (1.0f / 1024.0f) - mean * mean;
  float rstd = rsqrtf(var + 1e-5f);
  u32 pk[8];
#pragma unroll
  for (int i = 0; i < 8; ++i) {
    float w0 = ldf(w, L * 16 + 2 * i, f32), w1 = ldf(w, L * 16 + 2 * i + 1, f32);
    float b0 = ldf(b, L * 16 + 2 * i, f32), b1v = ldf(b, L * 16 + 2 * i + 1, f32);
    float v0 = (xv[2 * i] - mean) * rstd * w0 + b0;
    float v1 = (xv[2 * i + 1] - mean) * rstd * w1 + b1v;
    pk[i] = (u32)f2bf(v0) | ((u32)f2bf(v1) << 16);
  }
  u32x4 o0 = {pk[0], pk[1], pk[2], pk[3]};
  u32x4 o1 = {pk[4], pk[5], pk[6], pk[7]};
  *(u32x4*)(out + (size_t)row * 1024 + L * 16) = o0;
  *(u32x4*)(out + (size_t)row * 1024 + L * 16 + 8) = o1;
}

// -------- transpose+convert: dst[z][c][r] = (bf16)src_z[r][c], z-multiplexed --------
__global__ __launch_bounds__(256) void twc_kernel(const void* __restrict__ s0,
                                                  const void* __restrict__ s1,
                                                  const void* __restrict__ s2,
                                                  u16* __restrict__ dst, int sstride,
                                                  int dstride, size_t soff, size_t dzoff,
                                                  const int* __restrict__ flag) {
  __shared__ __align__(16) u16 tile[64][72];
  const bool f32 = flag[0] == 0;
  const void* src = blockIdx.z == 0 ? s0 : (blockIdx.z == 1 ? s1 : s2);
  u16* dz = dst + (size_t)blockIdx.z * dzoff;
  const int r0 = blockIdx.y * 64, c0 = blockIdx.x * 64;
  const int t = threadIdx.x;
  const int rr = t >> 3, cc = t & 7;
#pragma unroll
  for (int i = 0; i < 2; ++i) {
    int row = rr + i * 32;
    size_t idx = (size_t)(r0 + row) * sstride + c0 + cc * 8 + soff;
    if (f32) {
      const f32x4* s = (const f32x4*)((const float*)src + idx);
      f32x4 a = s[0], b = s[1];
      union { u16 t16[8]; u32x4 v; } u_;
#pragma unroll
      for (int j = 0; j < 4; ++j) { u_.t16[j] = f2bf(a[j]); u_.t16[4 + j] = f2bf(b[j]); }
      *(u32x4*)(&tile[row][cc * 8]) = u_.v;
    } else {
      *(u32x4*)(&tile[row][cc * 8]) = *(const u32x4*)((const u16*)src + idx);
    }
  }
  __syncthreads();
  u16* d = dz + (size_t)c0 * dstride + r0;
#pragma unroll
  for (int i = 0; i < 2; ++i) {
    int n = rr + i * 32;
    union { u16 t16[8]; u32x4 v; } u_;
#pragma unroll
    for (int j = 0; j < 8; ++j) u_.t16[j] = tile[cc * 8 + j][n];
    *(u32x4*)(d + (size_t)n * dstride + cc * 8) = u_.v;
  }
}

// ------------- GEMM: C(MxN) = A(MxK) * Bt(NxK)^T, tile TM x 128 --------------
enum { EP_NONE = 0, EP_RES = 2, EP_GELU = 3, EP_BIASRES = 4, EP_QKV = 5 };

template <int TM, int EPI, bool RESRAW, bool OUTFLEX>
__global__ __launch_bounds__(256, 2) void gemm_bt(
    const u16* __restrict__ A, const u16* __restrict__ Bt, void* __restrict__ Cv,
    int M, int N, int K, const void* __restrict__ bias, int boff,
    const void* __restrict__ res, const int* __restrict__ flag,
    u16* __restrict__ kout, u16* __restrict__ vtout) {
  constexpr int MT = TM / 32;  // acc tiles per wave in M
  __shared__ __align__(16) u16 lds[TM * 64 + 128 * 64];
  const int t = threadIdx.x;
  const int w = t >> 6, L = t & 63;
  const int quad = L >> 4, l16 = L & 15;
  const int m0 = blockIdx.y * TM, n0 = blockIdx.x * 128;
  const int wm = (TM == 128) ? (w >> 1) * 64 : (w & 1) * 32;
  const int wn = (TM == 128) ? (w & 1) * 64 : (w >> 1) * 64;
  const int srow = L >> 3, spc = L & 7;
  const int sc = spc ^ srow;
  constexpr int BBASE = TM * 64;

  f32x4 acc[MT][4] = {};
  const u16* Ab = A + (size_t)m0 * K;
  const u16* Bb = Bt + (size_t)n0 * K;

  for (int kt = 0; kt < K; kt += 64) {
#pragma unroll
    for (int r = 0; r < TM / 32; ++r) {
      int row = r * 32 + w * 8 + srow;
      async16(Ab + (size_t)row * K + kt + sc * 8, &lds[row * 64 + spc * 8]);
    }
#pragma unroll
    for (int r = 0; r < 4; ++r) {
      int row = r * 32 + w * 8 + srow;
      async16(Bb + (size_t)row * K + kt + sc * 8, &lds[BBASE + row * 64 + spc * 8]);
    }
    __syncthreads();
#pragma unroll
    for (int ks = 0; ks < 2; ++ks) {
      bf16x8 af[MT], bfr[4];
#pragma unroll
      for (int mt = 0; mt < MT; ++mt) {
        int row = wm + mt * 16 + l16;
        af[mt] = ld8(&lds[row * 64 + (((ks * 4 + quad) ^ (l16 & 7)) * 8)]);
      }
#pragma unroll
      for (int nt = 0; nt < 4; ++nt) {
        int row = wn + nt * 16 + l16;
        bfr[nt] = ld8(&lds[BBASE + row * 64 + (((ks * 4 + quad) ^ (l16 & 7)) * 8)]);
      }
#pragma unroll
      for (int mt = 0; mt < MT; ++mt)
#pragma unroll
        for (int nt = 0; nt < 4; ++nt)
          acc[mt][nt] =
              __builtin_amdgcn_mfma_f32_16x16x32_bf16(af[mt], bfr[nt], acc[mt][nt], 0, 0, 0);
    }
    __syncthreads();
  }

  const bool f32 = flag[0] == 0;
#pragma unroll
  for (int mt = 0; mt < MT; ++mt) {
#pragma unroll
    for (int nt = 0; nt < 4; ++nt) {
      int col = n0 + wn + nt * 16 + l16;
      float bv = 0.f;
      if (EPI == EP_GELU || EPI == EP_BIASRES) bv = ldf(bias, (size_t)boff + col, f32);
#pragma unroll
      for (int r = 0; r < 4; ++r) {
        int row = m0 + wm + mt * 16 + quad * 4 + r;
        float v = acc[mt][nt][r];
        if (EPI == EP_GELU) {
          v += bv;
          v = 0.5f * v * (1.0f + erff(v * 0.70710678118654752f));
        }
        if (EPI == EP_RES || EPI == EP_BIASRES) {
          size_t ri = (size_t)row * N + col;
          float rv = RESRAW ? ldf(res, ri, f32) : bf2f(((const u16*)res)[ri]);
          v += rv;
          if (EPI == EP_BIASRES) v += bv;
        }
        if (EPI == EP_QKV) {
          if (col < 1024) {
            ((u16*)Cv)[(size_t)row * 1024 + col] = f2bf(v * 0.125f);  // q, pre-scaled
          } else if (col < 2048) {
            kout[(size_t)row * 1024 + (col - 1024)] = f2bf(v);  // k
          } else {  // v stored transposed: vT[(b*8+h)*128+d][2048]
            int c2 = col - 2048;
            int bb = row >> 11, n = row & 2047, hh = c2 >> 7, d = c2 & 127;
            vtout[(size_t)((bb * 8 + hh) * 128 + d) * 2048 + n] = f2bf(v);
          }
        } else {
          size_t ci = (size_t)row * N + col;
          if (OUTFLEX && f32)
            ((float*)Cv)[ci] = v;
          else
            ((u16*)Cv)[ci] = f2bf(v);
        }
      }
    }
  }
}

// ---------------- Flash differential attention (R5 numerics + pipelined DMA) --------
// grid 512 = b(2) x h(8) x qtile(32 of 64 rows). 4 waves: comp=w>>1, rowhalf=(w&1)*32.
// LDS (u16): K[2][64][64] @0 | Vt[128][64] @8192 | P/Qstage[4][32][64] @16384
// 2 barriers/tile: barrier A (post-P) protects K WAR + orders P; stageK(ti+1)
// overlaps PV. barrier B (post-PV) protects V WAR + drains K(ti+1); stageV(ti+1)
// overlaps next QK+softmax. P region is wave-private (own rows only).
__global__ __launch_bounds__(256, 2) void attn_kernel(
    const u16* __restrict__ q, const u16* __restrict__ k, const u16* __restrict__ vT,
    const float* __restrict__ lamp, const void* __restrict__ subw,
    const int* __restrict__ flag, u16* __restrict__ o) {
  __shared__ __align__(16) u16 lds[24576];
  const int t = threadIdx.x, w = t >> 6, L = t & 63;
  const int quad = L >> 4, l16 = L & 15;
  const int bid = blockIdx.x;
  const int qt = bid & 31, h = (bid >> 5) & 7, b = bid >> 8;
  const int q0 = qt * 64;
  const int comp = w >> 1, rh = (w & 1) * 32;
  const int srow = L >> 3, spc = L & 7, sc = spc ^ srow;
  const u16* vb = vT + (size_t)(b * 8 + h) * (128 * 2048);
  const int pbase = 16384 + w * 2048;

  auto stageK = [&](int kt) {
#pragma unroll
    for (int r = 0; r < 4; ++r) {
      int row = r * 32 + w * 8 + srow;  // comp=row>>6, key=row&63
      int c_ = row >> 6, key = row & 63;
      async16(k + ((size_t)(b * 2048 + kt + key) * 1024 + (2 * h + c_) * 64 + sc * 8),
              &lds[row * 64 + spc * 8]);
    }
  };
  auto stageV = [&](int kt) {
#pragma unroll
    for (int r = 0; r < 4; ++r) {
      int dim = r * 32 + w * 8 + srow;  // 0..127
      async16(vb + (size_t)dim * 2048 + kt + sc * 8, &lds[8192 + dim * 64 + spc * 8]);
    }
  };

  stageK(0);
  stageV(0);
  // stage Q (both comps) into P region
#pragma unroll
  for (int r = 0; r < 4; ++r) {
    int row = r * 32 + w * 8 + srow;  // 0..127 : comp=row>>6, qrow=row&63
    int c_ = row >> 6, qr = row & 63;
    async16(q + ((size_t)(b * 2048 + q0 + qr) * 1024 + (2 * h + c_) * 64 + sc * 8),
            &lds[16384 + row * 64 + spc * 8]);
  }
  __syncthreads();  // all initial DMA (K0, V0, Q) drained
  bf16x8 qf[2][2];
#pragma unroll
  for (int mt = 0; mt < 2; ++mt)
#pragma unroll
    for (int ks = 0; ks < 2; ++ks) {
      int row = rh + mt * 16 + l16;
      qf[mt][ks] =
          ld8(&lds[16384 + comp * 4096 + row * 64 + (((ks * 4 + quad) ^ (l16 & 7)) * 8)]);
    }
  // no barrier: each wave's qf rows == its own (later) P rows; in-wave DS order

  float mst[2][4], lst[2][4];
#pragma unroll
  for (int mt = 0; mt < 2; ++mt)
#pragma unroll
    for (int r = 0; r < 4; ++r) { mst[mt][r] = -3.0e38f; lst[mt][r] = 0.f; }
  f32x4 oacc[2][8] = {};

  for (int ti = 0; ti < 32; ++ti) {
    // S = Q * Ktile^T for own comp (32 q rows per wave)
    f32x4 s[2][4] = {};
#pragma unroll
    for (int ks = 0; ks < 2; ++ks) {
      bf16x8 kf[4];
#pragma unroll
      for (int nt = 0; nt < 4; ++nt) {
        int row = nt * 16 + l16;
        kf[nt] = ld8(&lds[comp * 4096 + row * 64 + (((ks * 4 + quad) ^ (l16 & 7)) * 8)]);
      }
#pragma unroll
      for (int mt = 0; mt < 2; ++mt)
#pragma unroll
        for (int nt = 0; nt < 4; ++nt)
          s[mt][nt] = __builtin_amdgcn_mfma_f32_16x16x32_bf16(qf[mt][ks], kf[nt], s[mt][nt], 0, 0, 0);
    }

    // online softmax per owned row (R5 verbatim)
#pragma unroll
    for (int mt = 0; mt < 2; ++mt) {
#pragma unroll
      for (int r = 0; r < 4; ++r) {
        float mx = fmaxf(fmaxf(s[mt][0][r], s[mt][1][r]), fmaxf(s[mt][2][r], s[mt][3][r]));
        mx = fmaxf(mx, __shfl_xor(mx, 1));
        mx = fmaxf(mx, __shfl_xor(mx, 2));
        mx = fmaxf(mx, __shfl_xor(mx, 4));
        mx = fmaxf(mx, __shfl_xor(mx, 8));
        float mnew = fmaxf(mst[mt][r], mx);
        float al = exp2f((mst[mt][r] - mnew) * LOG2E);
        float ps = 0.f;
#pragma unroll
        for (int nt = 0; nt < 4; ++nt) {
          float p = exp2f((s[mt][nt][r] - mnew) * LOG2E);
          s[mt][nt][r] = p;
          ps += p;
        }
        ps += __shfl_xor(ps, 1);
        ps += __shfl_xor(ps, 2);
        ps += __shfl_xor(ps, 4);
        ps += __shfl_xor(ps, 8);
        lst[mt][r] = lst[mt][r] * al + ps;
        mst[mt][r] = mnew;
#pragma unroll
        for (int nt = 0; nt < 8; ++nt) oacc[mt][nt][r] *= al;
      }
    }

    // P (C-layout) -> LDS (A-layout readable), wave-private region
#pragma unroll
    for (int mt = 0; mt < 2; ++mt)
#pragma unroll
      for (int nt = 0; nt < 4; ++nt)
#pragma unroll
        for (int r = 0; r < 4; ++r) {
          int prow = mt * 16 + quad * 4 + r;
          int key = nt * 16 + l16;
          int pc = (key >> 3) ^ (prow & 7);
          lds[pbase + prow * 64 + pc * 8 + (key & 7)] = f2bf(s[mt][nt][r]);
        }
    __syncthreads();  // A: all QK reads of K(ti) done; P ordered; V(ti) resident
    if (ti + 1 < 32) stageK((ti + 1) * 64);  // overlaps PV

    // O += P * Vtile
#pragma unroll
    for (int ks = 0; ks < 2; ++ks) {
      bf16x8 pf[2];
#pragma unroll
      for (int mt = 0; mt < 2; ++mt) {
        int row = mt * 16 + l16;
        pf[mt] = ld8(&lds[pbase + row * 64 + (((ks * 4 + quad) ^ (l16 & 7)) * 8)]);
      }
#pragma unroll
      for (int nt = 0; nt < 8; ++nt) {
        int dim = nt * 16 + l16;
        bf16x8 vf = ld8(&lds[8192 + dim * 64 + (((ks * 4 + quad) ^ (l16 & 7)) * 8)]);
#pragma unroll
        for (int mt = 0; mt < 2; ++mt)
          oacc[mt][nt] = __builtin_amdgcn_mfma_f32_16x16x32_bf16(pf[mt], vf, oacc[mt][nt], 0, 0, 0);
      }
    }
    __syncthreads();  // B: all PV reads of V(ti) done; K(ti+1) DMA drained
    if (ti + 1 < 32) stageV((ti + 1) * 64);  // overlaps next QK + softmax
  }

  // normalize by l
#pragma unroll
  for (int mt = 0; mt < 2; ++mt)
#pragma unroll
    for (int r = 0; r < 4; ++r) {
      float inv = 1.0f / lst[mt][r];
#pragma unroll
      for (int nt = 0; nt < 8; ++nt) oacc[mt][nt][r] *= inv;
    }

  // combine: comp1 waves dump normalized O2 (fp32) to LDS; comp0 diff+RMS+store
  float* cb = (float*)lds;  // 64 rows x 132 floats
  if (comp == 1) {
#pragma unroll
    for (int mt = 0; mt < 2; ++mt)
#pragma unroll
      for (int nt = 0; nt < 8; ++nt)
#pragma unroll
        for (int r = 0; r < 4; ++r) {
          int rowc = rh + mt * 16 + quad * 4 + r;
          cb[rowc * 132 + nt * 16 + l16] = oacc[mt][nt][r];
        }
  }
  __syncthreads();
  if (comp == 0) {
    const bool f32 = flag[0] == 0;
    float lam = lamp[0];
#pragma unroll
    for (int mt = 0; mt < 2; ++mt)
#pragma unroll
      for (int r = 0; r < 4; ++r) {
        int rowc = rh + mt * 16 + quad * 4 + r;
        float dv[8];
        float sq = 0.f;
#pragma unroll
        for (int nt = 0; nt < 8; ++nt) {
          float d = oacc[mt][nt][r] - lam * cb[rowc * 132 + nt * 16 + l16];
          dv[nt] = d;
          sq += d * d;
        }
        sq += __shfl_xor(sq, 1);
        sq += __shfl_xor(sq, 2);
        sq += __shfl_xor(sq, 4);
        sq += __shfl_xor(sq, 8);
        float rms = rsqrtf(sq * (1.0f / 128.0f) + 1e-5f);
        size_t rowg = (size_t)(b * 2048 + q0 + rowc) * 1024 + h * 128;
#pragma unroll
        for (int nt = 0; nt < 8; ++nt) {
          int dim = nt * 16 + l16;
          o[rowg + dim] = f2bf(dv[nt] * rms * ldf(subw, dim, f32) * ONE_MINUS_LAM_INIT);
        }
      }
  }
}

// ---------------- host ----------------
extern "C" void kernel_launch(void* const* d_in, const int* in_sizes, int n_in,
                              void* d_out, int out_size, void* d_ws, size_t ws_size,
                              hipStream_t stream) {
  (void)in_sizes; (void)n_in; (void)out_size; (void)ws_size;
  const void* x = d_in[0];
  const void* ln1w = d_in[1];
  const void* ln1b = d_in[2];
  const void* Wq = d_in[3];
  const void* Wk = d_in[4];
  const void* Wv = d_in[5];
  const void* Wo = d_in[6];
  const void* lq1 = d_in[7];
  const void* lk1 = d_in[8];
  const void* lq2 = d_in[9];
  const void* lk2 = d_in[10];
  const void* subw = d_in[11];
  const void* ln2w = d_in[12];
  const void* ln2b = d_in[13];
  const void* W1 = d_in[14];
  const void* b1 = d_in[15];
  const void* W2 = d_in[16];
  const void* b2 = d_in[17];

  char* ws = (char*)d_ws;
  const size_t MB = 1u << 20;
  u16* A = (u16*)ws;               // h1 -> ob -> h2
  u16* B = (u16*)(ws + 8 * MB);    // q -> g (16MB contiguous over B+C)
  u16* C = (u16*)(ws + 16 * MB);   // k -> g(hi)
  u16* D = (u16*)(ws + 24 * MB);   // vT -> WoT -> W1Th|W2Th
  u16* E = (u16*)(ws + 32 * MB);   // WqT|WkT|WvT -> x2
  float* lam = (float*)(ws + 40 * MB);
  int* flag = (int*)(ws + 40 * MB + 64);
  u16* W2Th = D + 2097152;

  detect_kernel<<<dim3(1), dim3(64), 0, stream>>>((const u32*)x, flag);
  lam_kernel<<<dim3(1), dim3(64), 0, stream>>>(lq1, lk1, lq2, lk2, flag, lam);
  ln_kernel<true><<<dim3(1024), dim3(256), 0, stream>>>(x, ln1w, ln1b, flag, A);

  // Wq|Wk|Wv -> E concatenated n-major (3072 x 1024)
  twc_kernel<<<dim3(16, 16, 3), dim3(256), 0, stream>>>(Wq, Wk, Wv, E, 1024, 1024, 0,
                                                        1048576, flag);
  // fused q/k/v projection: q->B (pre-scaled), k->C, vT->D
  gemm_bt<64, EP_QKV, false, false><<<dim3(24, 64), dim3(256), 0, stream>>>(
      A, E, B, 4096, 3072, 1024, nullptr, 0, nullptr, flag, C, D);

  attn_kernel<<<dim3(512), dim3(256), 0, stream>>>(B, C, D, lam, subw, flag, A);

  // WoT -> D (vT dead); x2(bf16) = ob @ Wo + x -> E (Wq..WvT dead)
  twc_kernel<<<dim3(16, 16, 1), dim3(256), 0, stream>>>(Wo, Wo, Wo, D, 1024, 1024, 0, 0,
                                                        flag);
  gemm_bt<64, EP_RES, true, false><<<dim3(8, 64), dim3(256), 0, stream>>>(
      A, D, E, 4096, 1024, 1024, nullptr, 0, x, flag, nullptr, nullptr);
  ln_kernel<false><<<dim3(1024), dim3(256), 0, stream>>>(E, ln2w, ln2b, flag, A);

  // FFN in two FF-column halves; g = B..C (16MB contiguous), full-M launches
  for (int hh = 0; hh < 2; ++hh) {
    twc_kernel<<<dim3(32, 16, 1), dim3(256), 0, stream>>>(W1, W1, W1, D, 4096, 1024,
                                                          (size_t)hh * 2048, 0, flag);
    twc_kernel<<<dim3(16, 32, 1), dim3(256), 0, stream>>>(
        W2, W2, W2, W2Th, 1024, 2048, (size_t)hh * 2048 * 1024, 0, flag);
    gemm_bt<128, EP_GELU, false, false><<<dim3(16, 32), dim3(256), 0, stream>>>(
        A, D, B, 4096, 2048, 1024, b1, hh * 2048, nullptr, flag, nullptr, nullptr);
    if (hh == 0) {
      gemm_bt<64, EP_BIASRES, false, true><<<dim3(8, 64), dim3(256), 0, stream>>>(
          B, W2Th, d_out, 4096, 1024, 2048, b2, 0, E, flag, nullptr, nullptr);
    } else {
      gemm_bt<64, EP_RES, true, true><<<dim3(8, 64), dim3(256), 0, stream>>>(
          B, W2Th, d_out, 4096, 1024, 2048, nullptr, 0, d_out, flag, nullptr, nullptr);
    }
  }
}